// Round 3
// baseline (324.518 us; speedup 1.0000x reference)
//
#include <hip/hip_runtime.h>
#include <hip/hip_cooperative_groups.h>

namespace cg = cooperative_groups;

#define L_LEN 32768
#define QMAXF 127.0f

typedef __attribute__((ext_vector_type(4))) int v4i;

// wsf layout (floats):
//   [0..1536)    : phase-1 partials [ic][b][k]   (64*8*3)
//   [1536..1728) : rv_j = 1/(scale_j * s_x)
//   [1728]       : s_x * s_w
// wsa (byte offset 8192 in d_ws): A fragments, 3072 dwords (12288 B)

__global__ __launch_bounds__(256, 2) void fused_kernel(const float* __restrict__ x,
                                                       const float* __restrict__ w,
                                                       const float* __restrict__ bias,
                                                       float* __restrict__ wsf,
                                                       unsigned int* __restrict__ wsa,
                                                       float* __restrict__ out) {
    __shared__ int   bsm[3072];     // B fragments: [wave][3 ksteps][64 lanes][16 B]
    __shared__ float red[256];
    __shared__ float scl[192];
    __shared__ float redw[3][4];
    const int tid  = threadIdx.x;
    const int beta = blockIdx.x;    // 0..511
    cg::grid_group grid = cg::this_grid();

    // ================= phase 1: per-(ic,b) activation abs-max =================
    {
        const int ic = beta & 63, b = beta >> 6;
        const float4* row = (const float4*)(x + ((size_t)(b*64 + ic) << 15));
        float mA = 0.0f, mNF = 0.0f, mNL = 0.0f;  // all, no-first(t>0), no-last(t<L-1)
        for (int f = tid; f < 8192; f += 256) {
            float4 v = row[f];
            float ax = fabsf(v.x), ay = fabsf(v.y), az = fabsf(v.z), aw = fabsf(v.w);
            float m4 = fmaxf(fmaxf(ax, ay), fmaxf(az, aw));
            mA = fmaxf(mA, m4);
            if (f == 0) {
                mNF = fmaxf(mNF, fmaxf(ay, fmaxf(az, aw)));
                mNL = fmaxf(mNL, m4);
            } else if (f == 8191) {
                mNF = fmaxf(mNF, m4);
                mNL = fmaxf(mNL, fmaxf(ax, fmaxf(ay, az)));
            } else {
                mNF = fmaxf(mNF, m4);
                mNL = fmaxf(mNL, m4);
            }
        }
        #pragma unroll
        for (int off = 32; off; off >>= 1) {
            mA  = fmaxf(mA,  __shfl_down(mA,  off));
            mNF = fmaxf(mNF, __shfl_down(mNF, off));
            mNL = fmaxf(mNL, __shfl_down(mNL, off));
        }
        int wid = tid >> 6;
        if ((tid & 63) == 0) { redw[0][wid] = mA; redw[1][wid] = mNF; redw[2][wid] = mNL; }
        __syncthreads();
        if (tid == 0) {
            mA  = fmaxf(fmaxf(redw[0][0], redw[0][1]), fmaxf(redw[0][2], redw[0][3]));
            mNF = fmaxf(fmaxf(redw[1][0], redw[1][1]), fmaxf(redw[1][2], redw[1][3]));
            mNL = fmaxf(fmaxf(redw[2][0], redw[2][1]), fmaxf(redw[2][2], redw[2][3]));
            // k=0 uses x[-1..L-2] -> exclude last; k=1 all; k=2 uses x[1..L] -> exclude first
            float* p = wsf + (ic*8 + b)*3;
            p[0] = mNL; p[1] = mA; p[2] = mNF;
        }
        __threadfence();
    }
    grid.sync();

    // ================= phase 2: prep (block 0 only) =================
    if (beta == 0) {
        float ax = 0.0f, aw = 0.0f;
        if (tid < 192) {
            float wsc = 0.0f;
            #pragma unroll 8
            for (int o = 0; o < 64; ++o) wsc = fmaxf(wsc, fabsf(w[o*192 + tid]));
            int ic = tid / 3, k = tid - ic*3;
            float asc = 0.0f;
            #pragma unroll
            for (int b = 0; b < 8; ++b) asc = fmaxf(asc, wsf[(ic*8 + b)*3 + k]);
            float sc = sqrtf(asc) / sqrtf(wsc);    // act**0.5 / w**0.5
            if (sc == 0.0f) sc = 1.0f;
            scl[tid] = sc;
            ax = asc / sc;     // column max of |cols/scale| (monotone fp div)
            aw = wsc * sc;     // max |w*scale|
        }
        red[tid] = ax; __syncthreads();
        for (int s = 128; s; s >>= 1) { if (tid < s) red[tid] = fmaxf(red[tid], red[tid+s]); __syncthreads(); }
        float axm = red[0]; __syncthreads();
        red[tid] = aw; __syncthreads();
        for (int s = 128; s; s >>= 1) { if (tid < s) red[tid] = fmaxf(red[tid], red[tid+s]); __syncthreads(); }
        float awm = red[0];
        float s_x = (axm == 0.0f) ? 1.0f : axm / QMAXF;
        float s_w = (awm == 0.0f) ? 1.0f : awm / QMAXF;
        if (tid < 192) wsf[1536 + tid] = 1.0f / (scl[tid] * s_x);
        if (tid == 0)  wsf[1728] = s_x * s_w;
        __syncthreads();
        // quantize weights into MFMA A-fragment (16x16x64 i8) lane-chunk order
        for (int idx = tid; idx < 3072; idx += 256) {
            int oc = idx / 48, dwi = idx - oc*48, j0 = dwi*4;
            unsigned pk = 0;
            #pragma unroll
            for (int bb = 0; bb < 4; ++bb) {
                int j = j0 + bb;
                float q = rintf((w[oc*192 + j] * scl[j]) / s_w);  // ref op order
                q = fminf(fmaxf(q, -QMAXF), QMAXF);
                pk |= (((unsigned)(int)q) & 255u) << (8*bb);
            }
            int mt = oc >> 4, m = oc & 15, c = j0 >> 4, s = c >> 2, kq = c & 3;
            wsa[((mt*3 + s)*64 + kq*16 + m)*4 + ((j0 & 15) >> 2)] = pk;
        }
        __threadfence();
    }
    grid.sync();

    // ================= phase 3: conv over 8 batches, fixed t-range =================
    const int lane = tid & 63;
    const int wv   = tid >> 6;
    const int t0   = beta << 6;

    v4i afrag[12];
    const v4i* wsav = (const v4i*)wsa;
    #pragma unroll
    for (int i = 0; i < 12; ++i) afrag[i] = wsav[i*64 + lane];

    const float sxw = wsf[1728];
    const int tq  = tid & 15;      // owns t = 4*tq .. 4*tq+3 (block-local)
    const int icg = tid >> 4;      // owns ic = 4*icg .. 4*icg+3
    const int tb  = tq << 2;

    float rv[12];
    #pragma unroll
    for (int jj = 0; jj < 12; ++jj) rv[jj] = wsf[1536 + icg*12 + jj];

    const int rowq = (lane >> 4) << 2;
    float bv[4][4];
    #pragma unroll
    for (int mt = 0; mt < 4; ++mt)
        #pragma unroll
        for (int i = 0; i < 4; ++i) bv[mt][i] = bias[mt*16 + rowq + i];

    const v4i* bsmv = (const v4i*)bsm;

    for (int b = 0; b < 8; ++b) {
        // ---- stage + quantize x tile into B-fragment-sequential LDS ----
        float xv[4][6];            // [ici][t-1 .. t+4]
        #pragma unroll
        for (int ici = 0; ici < 4; ++ici) {
            const float* row = x + (((size_t)(b*64 + icg*4 + ici)) << 15) + t0 + tb;
            float4 mid = *(const float4*)row;
            float lm = (t0 + tb > 0)         ? row[-1] : 0.0f;
            float rp = (t0 + tb + 4 < L_LEN) ? row[4]  : 0.0f;
            xv[ici][0] = lm;    xv[ici][1] = mid.x; xv[ici][2] = mid.y;
            xv[ici][3] = mid.z; xv[ici][4] = mid.w; xv[ici][5] = rp;
        }
        #pragma unroll
        for (int dt = 0; dt < 4; ++dt) {
            int t  = tb + dt;
            int wt = t >> 4, n = t & 15;
            #pragma unroll
            for (int dw = 0; dw < 3; ++dw) {
                unsigned pk = 0;
                #pragma unroll
                for (int bb = 0; bb < 4; ++bb) {
                    int jloc = dw*4 + bb;       // j = 12*icg + jloc = 3*ic + k
                    int ici = jloc / 3, k = jloc - ici*3;
                    float q = rintf(xv[ici][dt + k] * rv[jloc]);
                    q = fminf(fmaxf(q, -QMAXF), QMAXF);
                    pk |= (((unsigned)(int)q) & 255u) << (8*bb);
                }
                int j0 = icg*12 + dw*4;
                int c = j0 >> 4, s = c >> 2, kq = c & 3;
                bsm[((wt*3 + s)*64 + kq*16 + n)*4 + ((j0 & 15) >> 2)] = (int)pk;
            }
        }
        __syncthreads();

        // ---- MFMA ----
        v4i acc[4];
        #pragma unroll
        for (int mt = 0; mt < 4; ++mt) acc[mt] = (v4i){0,0,0,0};
        #pragma unroll
        for (int s = 0; s < 3; ++s) {
            v4i bf = bsmv[(wv*3 + s)*64 + lane];
            #pragma unroll
            for (int mt = 0; mt < 4; ++mt)
                acc[mt] = __builtin_amdgcn_mfma_i32_16x16x64_i8(afrag[mt*3 + s], bf, acc[mt], 0, 0, 0);
        }

        // ---- epilogue: col=lane&15 -> t, row=(lane>>4)*4+i -> oc ----
        const int tg = t0 + (wv << 4) + (lane & 15);
        #pragma unroll
        for (int mt = 0; mt < 4; ++mt) {
            #pragma unroll
            for (int i = 0; i < 4; ++i) {
                int oc = mt*16 + rowq + i;
                out[(((size_t)(b*64 + oc)) << 15) + tg] = (float)acc[mt][i] * sxw + bv[mt][i];
            }
        }
        __syncthreads();   // protect bsm before next batch overwrites
    }
}

extern "C" void kernel_launch(void* const* d_in, const int* in_sizes, int n_in,
                              void* d_out, int out_size, void* d_ws, size_t ws_size,
                              hipStream_t stream) {
    const float* x    = (const float*)d_in[0];
    const float* w    = (const float*)d_in[1];
    const float* bias = (const float*)d_in[2];
    float* out = (float*)d_out;
    float* wsf = (float*)d_ws;
    unsigned int* wsa = (unsigned int*)((char*)d_ws + 8192);

    void* args[] = { (void*)&x, (void*)&w, (void*)&bias, (void*)&wsf, (void*)&wsa, (void*)&out };
    hipLaunchCooperativeKernel((const void*)fused_kernel, dim3(512), dim3(256), args, 0, stream);
}

// Round 4
// 164.539 us; speedup vs baseline: 1.9723x; 1.9723x over previous
//
#include <hip/hip_runtime.h>

#define L_LEN 32768
#define QMAXF 127.0f

typedef __attribute__((ext_vector_type(4))) int v4i;

// wsf layout (floats):
//   [0..1536)    : phase-1 partials [ic][b][k]  (64*8*3) — plain stores, no atomics
//   [1536..1728) : rv_j = 1/(scale_j * s_x)
//   [1728]       : s_x * s_w
// wsa (byte offset 8192): A fragments (quantized weights, i8, MFMA lane-chunk order)

__global__ __launch_bounds__(256) void actamax_kernel(const float* __restrict__ x,
                                                      float* __restrict__ wsf) {
    const int ic = blockIdx.x, b = blockIdx.y;
    const float4* row = (const float4*)(x + ((size_t)(b*64 + ic) << 15));
    float mA = 0.0f, mNF = 0.0f, mNL = 0.0f;   // all, no-first(t>0), no-last(t<L-1)
    for (int f = threadIdx.x; f < 8192; f += 256) {
        float4 v = row[f];
        float ax = fabsf(v.x), ay = fabsf(v.y), az = fabsf(v.z), aw = fabsf(v.w);
        float m4 = fmaxf(fmaxf(ax, ay), fmaxf(az, aw));
        mA = fmaxf(mA, m4);
        if (f == 0) {
            mNF = fmaxf(mNF, fmaxf(ay, fmaxf(az, aw)));
            mNL = fmaxf(mNL, m4);
        } else if (f == 8191) {
            mNF = fmaxf(mNF, m4);
            mNL = fmaxf(mNL, fmaxf(ax, fmaxf(ay, az)));
        } else {
            mNF = fmaxf(mNF, m4);
            mNL = fmaxf(mNL, m4);
        }
    }
    #pragma unroll
    for (int off = 32; off; off >>= 1) {
        mA  = fmaxf(mA,  __shfl_down(mA,  off));
        mNF = fmaxf(mNF, __shfl_down(mNF, off));
        mNL = fmaxf(mNL, __shfl_down(mNL, off));
    }
    __shared__ float red[3][4];
    int wid = threadIdx.x >> 6;
    if ((threadIdx.x & 63) == 0) { red[0][wid] = mA; red[1][wid] = mNF; red[2][wid] = mNL; }
    __syncthreads();
    if (threadIdx.x == 0) {
        mA  = fmaxf(fmaxf(red[0][0], red[0][1]), fmaxf(red[0][2], red[0][3]));
        mNF = fmaxf(fmaxf(red[1][0], red[1][1]), fmaxf(red[1][2], red[1][3]));
        mNL = fmaxf(fmaxf(red[2][0], red[2][1]), fmaxf(red[2][2], red[2][3]));
        // k=0 uses x[-1..L-2] -> exclude last; k=1 all; k=2 uses x[1..L] -> exclude first
        float* p = wsf + (ic*8 + b)*3;
        p[0] = mNL; p[1] = mA; p[2] = mNF;
    }
}

// One block: w_scale, scales, s_x/s_w, reciprocals, weight quant into A-fragment order.
__global__ __launch_bounds__(256) void prep_kernel(const float* __restrict__ w,
                                                   float* __restrict__ wsf,
                                                   unsigned int* __restrict__ wsa) {
    __shared__ float scl[192];
    __shared__ float red[256];
    const int tid = threadIdx.x;
    float ax = 0.0f, aw = 0.0f;
    if (tid < 192) {
        float wsc = 0.0f;
        #pragma unroll 8
        for (int o = 0; o < 64; ++o) wsc = fmaxf(wsc, fabsf(w[o*192 + tid]));
        int ic = tid / 3, k = tid - ic*3;
        float asc = 0.0f;
        #pragma unroll
        for (int b = 0; b < 8; ++b) asc = fmaxf(asc, wsf[(ic*8 + b)*3 + k]);
        float sc = sqrtf(asc) / sqrtf(wsc);    // act**0.5 / w**0.5
        if (sc == 0.0f) sc = 1.0f;
        scl[tid] = sc;
        ax = asc / sc;     // column max of |cols/scale| (monotone fp div)
        aw = wsc * sc;     // max |w*scale|
    }
    red[tid] = ax; __syncthreads();
    for (int s = 128; s; s >>= 1) { if (tid < s) red[tid] = fmaxf(red[tid], red[tid+s]); __syncthreads(); }
    float axm = red[0]; __syncthreads();
    red[tid] = aw; __syncthreads();
    for (int s = 128; s; s >>= 1) { if (tid < s) red[tid] = fmaxf(red[tid], red[tid+s]); __syncthreads(); }
    float awm = red[0];
    float s_x = (axm == 0.0f) ? 1.0f : axm / QMAXF;
    float s_w = (awm == 0.0f) ? 1.0f : awm / QMAXF;
    if (tid < 192) wsf[1536 + tid] = 1.0f / (scl[tid] * s_x);
    if (tid == 0)  wsf[1728] = s_x * s_w;
    __syncthreads();
    // quantize weights into MFMA A-fragment (16x16x64 i8) lane-chunk order
    for (int idx = tid; idx < 3072; idx += 256) {
        int oc = idx / 48, dwi = idx - oc*48, j0 = dwi*4;
        unsigned pk = 0;
        #pragma unroll
        for (int bb = 0; bb < 4; ++bb) {
            int j = j0 + bb;
            float q = rintf((w[oc*192 + j] * scl[j]) / s_w);  // ref op order
            q = fminf(fmaxf(q, -QMAXF), QMAXF);
            pk |= (((unsigned)(int)q) & 255u) << (8*bb);
        }
        int mt = oc >> 4, m = oc & 15, c = j0 >> 4, s = c >> 2, kq = c & 3;
        wsa[((mt*3 + s)*64 + kq*16 + m)*4 + ((j0 & 15) >> 2)] = pk;
    }
}

// Conv as i8 MFMA GEMM: D[oc][t] = sum_j qw[oc][j] * qx[j][t], j = ic*3+k.
// Block: 64 t x 64 oc x 1 batch; 4 waves, wave w owns t-range [16w,16w+16).
__global__ __launch_bounds__(256) void conv_mfma_kernel(const float* __restrict__ x,
                                                        const float* __restrict__ bias,
                                                        const float* __restrict__ wsf,
                                                        const v4i* __restrict__ wsa,
                                                        float* __restrict__ out) {
    __shared__ int bsm[3072];   // B fragments: [wave][3 ksteps][64 lanes][16 B]
    const int tid  = threadIdx.x;
    const int b    = blockIdx.y;
    const int t0   = blockIdx.x << 6;
    const int lane = tid & 63;
    const int w    = tid >> 6;

    // A fragments: 4 m-tiles x 3 k-steps, 16 B/lane each (precomputed order)
    v4i afrag[12];
    #pragma unroll
    for (int i = 0; i < 12; ++i) afrag[i] = wsa[i*64 + lane];

    // ---- stage + quantize x into B-fragment-sequential LDS ----
    const int tq  = tid & 15;      // owns t = 4*tq .. 4*tq+3 (block-local)
    const int icg = tid >> 4;      // owns ic = 4*icg .. 4*icg+3  (j = 12*icg..+11)
    const int tb  = tq << 2;

    float rv[12];
    #pragma unroll
    for (int jj = 0; jj < 12; ++jj) rv[jj] = wsf[1536 + icg*12 + jj];

    float xv[4][6];                // [ici][t-1 .. t+4]
    #pragma unroll
    for (int ici = 0; ici < 4; ++ici) {
        const float* row = x + (((size_t)(b*64 + icg*4 + ici)) << 15) + t0 + tb;
        float4 mid = *(const float4*)row;
        float lm = (t0 + tb > 0)           ? row[-1] : 0.0f;
        float rp = (t0 + tb + 4 < L_LEN)   ? row[4]  : 0.0f;
        xv[ici][0] = lm;   xv[ici][1] = mid.x; xv[ici][2] = mid.y;
        xv[ici][3] = mid.z; xv[ici][4] = mid.w; xv[ici][5] = rp;
    }

    #pragma unroll
    for (int dt = 0; dt < 4; ++dt) {
        int t  = tb + dt;
        int wt = t >> 4, n = t & 15;
        #pragma unroll
        for (int dw = 0; dw < 3; ++dw) {
            unsigned pk = 0;
            #pragma unroll
            for (int bb = 0; bb < 4; ++bb) {
                int jloc = dw*4 + bb;           // 0..11 ; j = 12*icg + jloc = 3*ic + k
                int ici = jloc / 3, k = jloc - ici*3;
                float q = rintf(xv[ici][dt + k] * rv[jloc]);
                q = fminf(fmaxf(q, -QMAXF), QMAXF);
                pk |= (((unsigned)(int)q) & 255u) << (8*bb);
            }
            int j0 = icg*12 + dw*4;
            int c = j0 >> 4, s = c >> 2, kq = c & 3;
            bsm[((wt*3 + s)*64 + kq*16 + n)*4 + ((j0 & 15) >> 2)] = (int)pk;
        }
    }
    __syncthreads();

    // ---- MFMA ----
    v4i acc[4];
    #pragma unroll
    for (int mt = 0; mt < 4; ++mt) acc[mt] = (v4i){0,0,0,0};
    const v4i* bsmv = (const v4i*)bsm;
    #pragma unroll
    for (int s = 0; s < 3; ++s) {
        v4i bf = bsmv[(w*3 + s)*64 + lane];
        #pragma unroll
        for (int mt = 0; mt < 4; ++mt)
            acc[mt] = __builtin_amdgcn_mfma_i32_16x16x64_i8(afrag[mt*3 + s], bf, acc[mt], 0, 0, 0);
    }

    // ---- epilogue: C/D layout col=lane&15 -> t, row=(lane>>4)*4+i -> oc ----
    const float sxw = wsf[1728];
    const int tg   = t0 + (w << 4) + (lane & 15);
    const int rowq = (lane >> 4) << 2;
    #pragma unroll
    for (int mt = 0; mt < 4; ++mt) {
        #pragma unroll
        for (int i = 0; i < 4; ++i) {
            int oc = mt*16 + rowq + i;
            out[(((size_t)(b*64 + oc)) << 15) + tg] = (float)acc[mt][i] * sxw + bias[oc];
        }
    }
}

extern "C" void kernel_launch(void* const* d_in, const int* in_sizes, int n_in,
                              void* d_out, int out_size, void* d_ws, size_t ws_size,
                              hipStream_t stream) {
    const float* x    = (const float*)d_in[0];
    const float* w    = (const float*)d_in[1];
    const float* bias = (const float*)d_in[2];
    float* out = (float*)d_out;
    float* wsf = (float*)d_ws;
    unsigned int* wsa = (unsigned int*)((char*)d_ws + 8192);

    hipLaunchKernelGGL(actamax_kernel,  dim3(64, 8),  dim3(256), 0, stream, x, wsf);
    hipLaunchKernelGGL(prep_kernel,     dim3(1),      dim3(256), 0, stream, w, wsf, wsa);
    hipLaunchKernelGGL(conv_mfma_kernel,dim3(512, 8), dim3(256), 0, stream, x, bias, wsf, (const v4i*)wsa, out);
}